// Round 6
// baseline (373.591 us; speedup 1.0000x reference)
//
#include <hip/hip_runtime.h>

// ---------------------------------------------------------------------------
// SegAwareMultiHeadAttention on MI355X (gfx950)
// B=32, N=577, HIDDEN=768, HEADS=12, HEAD_DIM=64
// cast/transpose -> QKV GEMM (bf16 MFMA, BK=64 DMA staging, XCD-remapped) ->
// V-transpose prepass -> flash attention v4 (S^T trick, P stays in regs) ->
// proj GEMM
// ---------------------------------------------------------------------------

typedef unsigned short bf16_t;
typedef __attribute__((ext_vector_type(8))) short short8;   // 8 bf16 = 16 B
typedef __attribute__((ext_vector_type(4))) short short4v;  // 4 bf16 = 8 B
typedef __attribute__((ext_vector_type(4))) float f32x4;    // MFMA C/D frag

#define B_    32
#define N_    577
#define BN_   18464
#define HID_  768
#define NH_   12
#define HD_   64
#define QKVC_ 2304
#define NPAD_ 640     // keys padded to 10 tiles of 64

__device__ __forceinline__ bf16_t f2bf(float f) {
  union { float f; unsigned u; } x; x.f = f;
  unsigned r = x.u + 0x7fffu + ((x.u >> 16) & 1u);
  return (bf16_t)(r >> 16);
}

// float4 -> 4x bf16, round-half-up (P values are positive, well-conditioned)
__device__ __forceinline__ short4v pack4_bf16(f32x4 p) {
  short4v o;
  #pragma unroll
  for (int j = 0; j < 4; ++j) {
    union { float f; unsigned u; } c; c.f = p[j];
    o[j] = (short)((c.u + 0x8000u) >> 16);
  }
  return o;
}

// ---------------------------------------------------------------------------
__global__ __launch_bounds__(256) void cast_kernel(const float* __restrict__ in,
                                                   bf16_t* __restrict__ out, int n4) {
  int i = blockIdx.x * 256 + threadIdx.x;
  if (i >= n4) return;
  float4 v = ((const float4*)in)[i];
  ushort4 o;
  o.x = f2bf(v.x); o.y = f2bf(v.y); o.z = f2bf(v.z); o.w = f2bf(v.w);
  ((ushort4*)out)[i] = o;
}

// in fp32 [R][C] -> out bf16 [C][R]
__global__ __launch_bounds__(256) void transpose_cast_kernel(const float* __restrict__ in,
                                                             bf16_t* __restrict__ out,
                                                             int R, int C) {
  __shared__ float tile[32][33];
  int c0 = blockIdx.x * 32, r0 = blockIdx.y * 32;
  int tx = threadIdx.x, ty = threadIdx.y;
  #pragma unroll
  for (int i = ty; i < 32; i += 8)
    tile[i][tx] = in[(size_t)(r0 + i) * C + c0 + tx];
  __syncthreads();
  #pragma unroll
  for (int i = ty; i < 32; i += 8)
    out[(size_t)(c0 + i) * R + r0 + tx] = f2bf(tile[tx][i]);
}

// ---------------------------------------------------------------------------
// GEMM: C[M][Nc] = A[M][768] * Bt[Nc][768]^T + bias. 128x128 tile, BK=64.
// global_load_lds width=16 staging, source-side XOR swizzle, panel remap.
// (unchanged — 0 bank conflicts, panel remap keeps A-strip in L2)
// ---------------------------------------------------------------------------
template <int OUT_BF16>
__global__ __launch_bounds__(256, 3) void gemm_bf16_kernel(
    const bf16_t* __restrict__ A,
    const bf16_t* __restrict__ Bt,
    const float* __restrict__ bias,
    void* __restrict__ Cout,
    int M, int Nc) {
  __shared__ bf16_t As[128 * 64];
  __shared__ bf16_t Bs[128 * 64];

  const int tid  = threadIdx.x;
  const int lane = tid & 63, w = tid >> 6;
  const int quad = lane >> 4, l16 = lane & 15;

  const int Mb = (M + 127) >> 7;
  const int Nb = Nc >> 7;
  const int np_full = Mb >> 3;
  const int rem = Mb - np_full * 8;
  int bid = blockIdx.x;
  int m_blk, n_blk;
  int body = np_full * 8 * Nb;
  if (bid < body) {
    int p = bid / (8 * Nb), local = bid % (8 * Nb);
    m_blk = p * 8 + (local & 7);
    n_blk = local >> 3;
  } else {
    int t = bid - body;
    m_blk = np_full * 8 + t % rem;
    n_blk = t / rem;
  }
  const int m0 = m_blk * 128, n0 = n_blk * 128;
  const int wm = (w >> 1) * 64, wn = (w & 1) * 64;

  f32x4 acc[4][4];
  #pragma unroll
  for (int i = 0; i < 4; ++i)
    #pragma unroll
    for (int j = 0; j < 4; ++j)
      acc[i][j] = (f32x4){0.f, 0.f, 0.f, 0.f};

  for (int kt = 0; kt < 768; kt += 64) {
    __syncthreads();
    #pragma unroll
    for (int it = 0; it < 4; ++it) {
      int gi = it * 256 + tid;
      int row = gi >> 3, chp = gi & 7;
      int ch = chp ^ (row & 7);
      int gm = m0 + row; if (gm >= M) gm = M - 1;
      __builtin_amdgcn_global_load_lds(
          (const __attribute__((address_space(1))) unsigned int*)(A + (size_t)gm * 768 + kt + ch * 8),
          (__attribute__((address_space(3))) unsigned int*)(As + gi * 8),
          16, 0, 0);
      int gn = n0 + row;
      __builtin_amdgcn_global_load_lds(
          (const __attribute__((address_space(1))) unsigned int*)(Bt + (size_t)gn * 768 + kt + ch * 8),
          (__attribute__((address_space(3))) unsigned int*)(Bs + gi * 8),
          16, 0, 0);
    }
    __syncthreads();

    #pragma unroll
    for (int ks = 0; ks < 2; ++ks) {
      short8 af[4], bfr[4];
      #pragma unroll
      for (int i = 0; i < 4; ++i) {
        int row = wm + i * 16 + l16;
        int c = ks * 4 + quad;
        af[i] = *(const short8*)(As + row * 64 + (c ^ (row & 7)) * 8);
      }
      #pragma unroll
      for (int j = 0; j < 4; ++j) {
        int row = wn + j * 16 + l16;
        int c = ks * 4 + quad;
        bfr[j] = *(const short8*)(Bs + row * 64 + (c ^ (row & 7)) * 8);
      }
      #pragma unroll
      for (int i = 0; i < 4; ++i)
        #pragma unroll
        for (int j = 0; j < 4; ++j)
          acc[i][j] = __builtin_amdgcn_mfma_f32_16x16x32_bf16(af[i], bfr[j], acc[i][j], 0, 0, 0);
    }
  }

  #pragma unroll
  for (int i = 0; i < 4; ++i) {
    int mrow_base = m0 + wm + i * 16 + quad * 4;
    #pragma unroll
    for (int j = 0; j < 4; ++j) {
      int col = n0 + wn + j * 16 + l16;
      float bs = bias[col];
      #pragma unroll
      for (int r = 0; r < 4; ++r) {
        int row = mrow_base + r;
        if (row < M) {
          float v = acc[i][j][r] + bs;
          if (OUT_BF16)
            ((bf16_t*)Cout)[(size_t)row * Nc + col] = f2bf(v);
          else
            ((float*)Cout)[(size_t)row * Nc + col] = v;
        }
      }
    }
  }
}

// ---------------------------------------------------------------------------
// V transpose prepass: qkv V-slice [key][d] -> vT[bh][d=64][NPAD_ keys]
// ---------------------------------------------------------------------------
__global__ __launch_bounds__(256) void vt_kernel(const bf16_t* __restrict__ qkv,
                                                 bf16_t* __restrict__ vT) {
  const int t = blockIdx.x, h = blockIdx.y, b = blockIdx.z;
  const int tid = threadIdx.x;
  __shared__ bf16_t Ls[64 * 65];
  const int kv0 = t * 64;
  const bf16_t* Vp = qkv + (size_t)b * N_ * QKVC_ + 2 * HID_ + h * HD_;

  #pragma unroll
  for (int it = 0; it < 2; ++it) {
    int idx = it * 256 + tid;
    int row = idx >> 3, ch = idx & 7;
    int krow = kv0 + row; if (krow > N_ - 1) krow = N_ - 1;
    short8 v8 = *(const short8*)(Vp + (size_t)krow * QKVC_ + ch * 8);
    #pragma unroll
    for (int j = 0; j < 8; ++j)
      Ls[(ch * 8 + j) * 65 + row] = (bf16_t)v8[j];
  }
  __syncthreads();
  bf16_t* outp = vT + ((size_t)(b * NH_ + h) * HD_) * NPAD_;
  #pragma unroll
  for (int it = 0; it < 2; ++it) {
    int idx = it * 256 + tid;
    int d = idx >> 3, kc = idx & 7;
    short8 o8;
    #pragma unroll
    for (int j = 0; j < 8; ++j)
      o8[j] = (short)Ls[d * 65 + kc * 8 + j];
    *(short8*)(outp + (size_t)d * NPAD_ + kv0 + kc * 8) = o8;
  }
}

// ---------------------------------------------------------------------------
// Flash attention v4. S^T trick: S^T = K*Q^T (swapped MFMA operands) puts
// qrow in l16, keys in quad*4+r -- which IS the A-operand layout of the
// 16x16x16 MFMA. P therefore never touches LDS: exp2 in regs, pack to bf16,
// feed mfma_f32_16x16x16bf16_1k directly. V B-frags are b64 reads from the
// [d][key] LDS tile. lsum is one scalar/lane (qrow = l16); cross-quad
// reduce + broadcast shuffles only in the epilogue.
// Double-buffered K/V (register prefetch, 1 barrier/tile). LDS 36.9 KB ->
// 4 blocks/CU.
// ---------------------------------------------------------------------------
__global__ __launch_bounds__(256, 4) void attn_kernel(
    const bf16_t* __restrict__ qkv,       // [BN][2304]
    const bf16_t* __restrict__ vT,        // [bh][64][NPAD_]
    const float* __restrict__ seg_bias,   // [B][576]
    const float* __restrict__ seg_scale,  // [1]
    bf16_t* __restrict__ out) {           // [BN][768]
  const int bid  = blockIdx.x;
  const int pair = bid % (B_ * NH_);
  const int qt   = bid / (B_ * NH_);     // 0..4
  const int h    = pair % NH_;
  const int b    = pair / NH_;
  const int tid = threadIdx.x;
  const int w = tid >> 6, lane = tid & 63;
  const int quad = lane >> 4, l16 = lane & 15;

  __shared__ bf16_t Ks[2][64 * 72];
  __shared__ bf16_t Vt[2][64 * 72];

  const bf16_t* Qbase = qkv + (size_t)b * N_ * QKVC_ + h * HD_;
  const bf16_t* Kbase = Qbase + HID_;
  const bf16_t* Vtb   = vT + ((size_t)(b * NH_ + h) * HD_) * NPAD_;

  const int q0 = qt * 128 + w * 32;
  short8 qf[2][2];
  #pragma unroll
  for (int mi = 0; mi < 2; ++mi) {
    int qr = q0 + mi * 16 + l16;
    if (qr > N_ - 1) qr = N_ - 1;
    qf[mi][0] = *(const short8*)(Qbase + (size_t)qr * QKVC_ + quad * 8);
    qf[mi][1] = *(const short8*)(Qbase + (size_t)qr * QKVC_ + 32 + quad * 8);
  }
  // fold scale*log2(e) into Q (one extra bf16 rounding on Q, negligible)
  const float qsc = 0.125f * 1.44269504f;
  #pragma unroll
  for (int mi = 0; mi < 2; ++mi)
    #pragma unroll
    for (int c = 0; c < 2; ++c)
      #pragma unroll
      for (int j = 0; j < 8; ++j) {
        unsigned u = ((unsigned)(unsigned short)qf[mi][c][j]) << 16;
        union { unsigned u; float f; } x; x.u = u;
        qf[mi][c][j] = (short)f2bf(x.f * qsc);
      }

  f32x4 o[2][4];
  float lsum[2] = {0.f, 0.f};
  #pragma unroll
  for (int mi = 0; mi < 2; ++mi)
    #pragma unroll
    for (int j = 0; j < 4; ++j)
      o[mi][j] = (f32x4){0.f, 0.f, 0.f, 0.f};

  const float ssl = seg_scale[0] * 1.44269504f;
  const bool bias_lane = (qt == 0 && w == 0 && l16 == 0);  // CLS q-row holders

  // staging geometry: 512 granules = 64 rows x 8 chunks, 2 per thread
  const int srow = tid >> 3;          // 0..31 (it adds +32)
  const int sch  = tid & 7;

  // preload tile 0
  short8 kpre[2], vpre[2];
  #pragma unroll
  for (int it = 0; it < 2; ++it) {
    int row = it * 32 + srow;
    int krow = row; if (krow > N_ - 1) krow = N_ - 1;
    kpre[it] = *(const short8*)(Kbase + (size_t)krow * QKVC_ + sch * 8);
    vpre[it] = *(const short8*)(Vtb + (size_t)row * NPAD_ + sch * 8);
  }
  #pragma unroll
  for (int it = 0; it < 2; ++it) {
    int row = it * 32 + srow;
    *(short8*)(&Ks[0][0] + row * 72 + sch * 8) = kpre[it];
    *(short8*)(&Vt[0][0] + row * 72 + sch * 8) = vpre[it];
  }
  __syncthreads();

  for (int t = 0; t < 10; ++t) {
    const int cur = t & 1;
    const int kv0 = t * 64;
    const bf16_t* ks = &Ks[cur][0];
    const bf16_t* vt = &Vt[cur][0];

    // issue prefetch for t+1 (latency hidden behind compute below)
    if (t < 9) {
      const int kv1 = kv0 + 64;
      #pragma unroll
      for (int it = 0; it < 2; ++it) {
        int row = it * 32 + srow;
        int krow = kv1 + row; if (krow > N_ - 1) krow = N_ - 1;
        kpre[it] = *(const short8*)(Kbase + (size_t)krow * QKVC_ + sch * 8);
        vpre[it] = *(const short8*)(Vtb + (size_t)row * NPAD_ + kv1 + sch * 8);
      }
    }

    // S^T = K Q^T : lane holds S^T[key=quad*4+r (+16*sub)][qrow=l16]
    f32x4 s[2][4];
    #pragma unroll
    for (int mi = 0; mi < 2; ++mi)
      #pragma unroll
      for (int sub = 0; sub < 4; ++sub)
        s[mi][sub] = (f32x4){0.f, 0.f, 0.f, 0.f};
    #pragma unroll
    for (int sub = 0; sub < 4; ++sub) {
      short8 k0 = *(const short8*)(ks + (sub * 16 + l16) * 72 + quad * 8);
      short8 k1 = *(const short8*)(ks + (sub * 16 + l16) * 72 + 32 + quad * 8);
      #pragma unroll
      for (int mi = 0; mi < 2; ++mi) {
        s[mi][sub] = __builtin_amdgcn_mfma_f32_16x16x32_bf16(k0, qf[mi][0], s[mi][sub], 0, 0, 0);
        s[mi][sub] = __builtin_amdgcn_mfma_f32_16x16x32_bf16(k1, qf[mi][1], s[mi][sub], 0, 0, 0);
      }
    }

    // rare CLS-row bias: only lanes with l16==0 of wave 0 of qt==0 blocks
    if (bias_lane) {
      #pragma unroll
      for (int sub = 0; sub < 4; ++sub)
        #pragma unroll
        for (int r = 0; r < 4; ++r) {
          int key = kv0 + sub * 16 + quad * 4 + r;
          if (key >= 1 && key < N_)
            s[0][sub][r] += seg_bias[b * (N_ - 1) + key - 1] * ssl;
        }
    }

    // softmax: p = exp2(s); mask only the (uniform) last tile; pack to A-frags
    short4v pf[2][4];
    #pragma unroll
    for (int mi = 0; mi < 2; ++mi)
      #pragma unroll
      for (int sub = 0; sub < 4; ++sub) {
        f32x4 p4;
        #pragma unroll
        for (int r = 0; r < 4; ++r) {
          float p = exp2f(s[mi][sub][r]);
          if (t == 9) {
            int key = kv0 + sub * 16 + quad * 4 + r;
            if (key >= N_) p = 0.f;
          }
          lsum[mi] += p;
          p4[r] = p;
        }
        pf[mi][sub] = pack4_bf16(p4);
      }

    // PV: O += P V via 16x16x16 (P A-frags direct from regs; V b64 from LDS)
    #pragma unroll
    for (int ds = 0; ds < 4; ++ds) {
      #pragma unroll
      for (int sub = 0; sub < 4; ++sub) {
        short4v vb = *(const short4v*)(vt + (ds * 16 + l16) * 72 + sub * 16 + quad * 4);
        #pragma unroll
        for (int mi = 0; mi < 2; ++mi)
          o[mi][ds] = __builtin_amdgcn_mfma_f32_16x16x16bf16_1k(pf[mi][sub], vb, o[mi][ds], 0, 0, 0);
      }
    }

    // write prefetch to the other buffer; single barrier covers RAW + WAR
    if (t < 9) {
      bf16_t* ksn = &Ks[1 - cur][0];
      bf16_t* vtn = &Vt[1 - cur][0];
      #pragma unroll
      for (int it = 0; it < 2; ++it) {
        int row = it * 32 + srow;
        *(short8*)(ksn + row * 72 + sch * 8) = kpre[it];
        *(short8*)(vtn + row * 72 + sch * 8) = vpre[it];
      }
    }
    __syncthreads();
  }

  // epilogue: reduce lsum across quads, broadcast per-row inverse, store
  #pragma unroll
  for (int mi = 0; mi < 2; ++mi) {
    float l = lsum[mi];
    l += __shfl_xor(l, 16);
    l += __shfl_xor(l, 32);     // now: lane holds total for qrow = mi*16 + l16
    #pragma unroll
    for (int r = 0; r < 4; ++r) {
      int rowl = quad * 4 + r;                  // local q-row of o[mi][.][r]
      float lr = __shfl(l, (lane & 48) + rowl); // total for that q-row
      float inv = 1.0f / lr;
      int row = q0 + mi * 16 + rowl;
      if (row < N_) {
        size_t base = ((size_t)b * N_ + row) * HID_ + h * HD_;
        #pragma unroll
        for (int ds = 0; ds < 4; ++ds)
          out[base + ds * 16 + l16] = f2bf(o[mi][ds][r] * inv);
      }
    }
  }
}

// ---------------------------------------------------------------------------
// ws layout (bytes):
//   xb     bf16[BN*768]     @ 0            (28,360,704)  -- reused as attnb
//   wqkvT  bf16[2304*768]   @ 28,360,704   ( 3,538,944)
//   wprojT bf16[768*768]    @ 31,899,648   ( 1,179,648)
//   qkvb   bf16[BN*2304]    @ 33,079,296   (85,082,112)
//   vT     bf16[384*64*640] @ 118,161,408  (31,457,280)
//   total 149,618,688 B
// ---------------------------------------------------------------------------
extern "C" void kernel_launch(void* const* d_in, const int* in_sizes, int n_in,
                              void* d_out, int out_size, void* d_ws, size_t ws_size,
                              hipStream_t stream) {
  const float* x         = (const float*)d_in[0];
  const float* seg_bias  = (const float*)d_in[1];
  const float* w_qkv     = (const float*)d_in[2];
  const float* b_qkv     = (const float*)d_in[3];
  const float* w_proj    = (const float*)d_in[4];
  const float* b_proj    = (const float*)d_in[5];
  const float* seg_scale = (const float*)d_in[6];

  char* ws = (char*)d_ws;
  bf16_t* xb     = (bf16_t*)ws;
  bf16_t* wqkvT  = (bf16_t*)(ws + 28360704);
  bf16_t* wprojT = (bf16_t*)(ws + 31899648);
  bf16_t* qkvb   = (bf16_t*)(ws + 33079296);
  bf16_t* vT     = (bf16_t*)(ws + 118161408);
  bf16_t* attnb  = xb;

  cast_kernel<<<(BN_ * HID_ / 4) / 256, 256, 0, stream>>>(x, xb, BN_ * HID_ / 4);
  dim3 tb(32, 8);
  transpose_cast_kernel<<<dim3(QKVC_ / 32, HID_ / 32), tb, 0, stream>>>(w_qkv, wqkvT, HID_, QKVC_);
  transpose_cast_kernel<<<dim3(HID_ / 32, HID_ / 32), tb, 0, stream>>>(w_proj, wprojT, HID_, HID_);

  gemm_bf16_kernel<1><<<145 * (QKVC_ / 128), 256, 0, stream>>>(
      xb, wqkvT, b_qkv, (void*)qkvb, BN_, QKVC_);

  vt_kernel<<<dim3(10, NH_, B_), 256, 0, stream>>>(qkvb, vT);

  attn_kernel<<<5 * NH_ * B_, 256, 0, stream>>>(qkvb, vT, seg_bias, seg_scale, attnb);

  gemm_bf16_kernel<0><<<145 * (HID_ / 128), 256, 0, stream>>>(
      attnb, wprojT, b_proj, d_out, BN_, HID_);
}